// Round 13
// baseline (1326.793 us; speedup 1.0000x reference)
//
#include <hip/hip_runtime.h>

// ---------- Swin block constants ----------
#define Bb   32
#define Hh   56
#define Ww_  56
#define Cc   512
#define HEADS 16
#define WS   7
#define SS   3
#define Nn   49          // window area
#define HD   32          // head dim
#define HID  2048
#define NWIN 2048        // B * nW
#define NTOK 100352      // B*H*W = NWIN*Nn
#define NTOKP 100416     // NTOK + 64 (pad rows so window-relative reads never go OOB)

typedef __attribute__((ext_vector_type(4))) float f32x4;
typedef __attribute__((ext_vector_type(8))) short bf16x8;

#define AS1 __attribute__((address_space(1)))
#define AS3 __attribute__((address_space(3)))

__device__ __forceinline__ ushort f2bf(float x) {
  union { float f; unsigned u; } un; un.f = x;
  unsigned u = un.u;
  return (ushort)((u + 0x7fffu + ((u >> 16) & 1u)) >> 16);
}

// ---------- weight convert to MFMA-fragment order ----------
// Bf[((n0*(K/32) + kk)*64 + lane)*8 + e] = bf16( W[(n0*16 + (lane&15))*K + kk*32 + (lane>>4)*8 + e] )
// Coalesced source reads; scattered-ish writes (write-combine absorbs).
__device__ __forceinline__ void cvt_frag_seg(const float* __restrict__ s, ushort* __restrict__ d,
                                             int N, int K, int tid0, int stride) {
  int nch = (N * K) >> 3;
  int kc = K >> 3;            // 8-elem chunks per row
  int kkt = K >> 5;
  for (int c = tid0; c < nch; c += stride) {
    int row = c / kc, col8 = c - row * kc;
    int n0 = row >> 4, l15 = row & 15;
    int kk = col8 >> 2, lhi = col8 & 3;
    int lane = (lhi << 4) | l15;
    const float* sp = s + (size_t)c * 8;
    ushort* dp = d + (((size_t)(n0 * kkt + kk) * 64 + lane) * 8);
    #pragma unroll
    for (int e = 0; e < 8; ++e) dp[e] = f2bf(sp[e]);
  }
}

__global__ void cvtwf_kern(const float* __restrict__ s0, ushort* __restrict__ d0,
                           const float* __restrict__ s1, ushort* __restrict__ d1,
                           const float* __restrict__ s2, ushort* __restrict__ d2,
                           const float* __restrict__ s3, ushort* __restrict__ d3) {
  int tid0 = blockIdx.x * 256 + threadIdx.x;
  int stride = gridDim.x * 256;
  cvt_frag_seg(s0, d0, 1536, 512, tid0, stride);
  cvt_frag_seg(s1, d1, 512, 512, tid0, stride);
  cvt_frag_seg(s2, d2, 2048, 512, tid0, stride);
  cvt_frag_seg(s3, d3, 512, 2048, tid0, stride);
}

// bias in fragment order: be2[h][q][l15][n] (n -> key = n*16+l15); pads = 0 (masked later)
__global__ void prep_bias_kern(const float* __restrict__ table, float* __restrict__ be2) {
  int idx = blockIdx.x * 256 + threadIdx.x;  // 16*64*64 = 65536
  int h = idx >> 12, q = (idx >> 6) & 63, t = idx & 63;
  int l15 = t >> 2, n = t & 3;
  int key = n * 16 + l15;
  float v = 0.f;
  if (q < Nn && key < Nn) {
    int qi = q / 7, qj = q - qi * 7;
    int ki = key / 7, kj = key - ki * 7;
    v = table[((qi - ki + 6) * 13 + (qj - kj + 6)) * HEADS + h];
  }
  be2[idx] = v;
}

// ---------- LayerNorm (+ optional shift+window permute), fp32 in -> bf16 out ----------
template<int MODE>
__global__ __launch_bounds__(256) void ln_kern(const float* __restrict__ x,
    const float* __restrict__ g, const float* __restrict__ bsh,
    ushort* __restrict__ out)
{
  int row  = blockIdx.x * 4 + (threadIdx.x >> 6);
  int lane = threadIdx.x & 63;
  const float* src;
  if (MODE == 0) {
    unsigned w = (unsigned)row / 49u, n = (unsigned)row - w * 49u;
    unsigned bb = w >> 6, wi = w & 63;
    unsigned wh = wi >> 3, ww = wi & 7;
    unsigned i = n / 7u, j = n - i * 7u;
    unsigned sr = wh * 7 + i + SS; if (sr >= Hh) sr -= Hh;   // roll(-3)
    unsigned sc = ww * 7 + j + SS; if (sc >= Ww_) sc -= Ww_;
    src = x + ((size_t)(bb * Hh + sr) * Ww_ + sc) * Cc;
  } else {
    src = x + (size_t)row * Cc;
  }
  int c = lane * 8;
  f32x4 v0 = *(const f32x4*)(src + c);
  f32x4 v1 = *(const f32x4*)(src + c + 4);
  float s = 0.f, s2 = 0.f;
  #pragma unroll
  for (int e = 0; e < 4; ++e) { s += v0[e]; s2 += v0[e]*v0[e]; s += v1[e]; s2 += v1[e]*v1[e]; }
  #pragma unroll
  for (int off = 32; off; off >>= 1) { s += __shfl_xor(s, off); s2 += __shfl_xor(s2, off); }
  float mu = s * (1.f / 512.f);
  float rstd = rsqrtf(s2 * (1.f / 512.f) - mu * mu + 1e-5f);
  bf16x8 r;
  #pragma unroll
  for (int e = 0; e < 8; ++e) {
    float xv = (e < 4) ? v0[e] : v1[e - 4];
    r[e] = (short)f2bf((xv - mu) * rstd * g[c + e] + bsh[c + e]);
  }
  *(bf16x8*)(out + (size_t)row * Cc + c) = r;
}

// ---------- GEMM 128x128, 4 waves, BK=64: A via LDS (16 KB), B streamed from L2 ----------
// B is pre-converted to MFMA-fragment order, so each wave's B-frag is one coalesced
// global_load_dwordx4 (lane*16B) — no LDS, no ds_read, no staging for B. Per iter:
// 4 A global_load_lds + 8 coalesced B reg-loads + 8 A ds_reads + 32 MFMA; the
// __syncthreads drain covers half the bytes of R12. Plain barriers, no asm (m141).
// A-side both-sides chunk swizzle (rule #21) unchanged.
// EPI 0: QKV scatter (Q/K head-major, V^T windowed)  EPI 1: fast GELU->bf16
// EPI 2: proj+unshift+resid->f32  EPI 3: += f32
template<int EPI>
__global__ __launch_bounds__(256, 2) void gemm_kern(
    const ushort* __restrict__ A, const ushort* __restrict__ Bf,
    const float* __restrict__ bias, int M, int N, int K,
    void* __restrict__ outp, const float* __restrict__ resid,
    ushort* __restrict__ qb, ushort* __restrict__ kb, ushort* __restrict__ vb)
{
  __shared__ ushort As[128 * 64];
  const int tid = threadIdx.x;
  const int wave = tid >> 6, lane = tid & 63;
  const int l15 = lane & 15, lhi = lane >> 4;
  const int sw7 = l15 & 7;                    // fragment row & 7

  // T1: bijective XCD swizzle on flattened grid (nwg % 8 == 0 for all our grids)
  int gx = gridDim.x;
  int nwg = gx * gridDim.y;
  int orig = blockIdx.y * gx + blockIdx.x;
  int cpx = nwg >> 3;
  int wg = (orig & 7) * cpx + (orig >> 3);
  int bx = wg % gx, by = wg / gx;
  const int brow = by * 128, bcol = bx * 128;

  // wave -> 64x64 output sub-tile (2x2 wave grid)
  const int wr = (wave >> 1) * 64, wc = (wave & 1) * 64;

  const int srow = lane >> 3;                 // 0..7
  const int schk = ((lane & 7) ^ srow) * 8;   // pre-swizzled 16B-chunk offset (elems)
  const ushort* aG = A + (size_t)(brow + srow) * K + schk;

  const int kkt = K >> 5;
  const int nb0 = (bcol + wc) >> 4;           // wave's base 16-col group
  const ushort* bW = Bf + (size_t)nb0 * kkt * 512 + (size_t)lane * 8;

  f32x4 acc[4][4];
  #pragma unroll
  for (int m = 0; m < 4; ++m)
    #pragma unroll
    for (int n = 0; n < 4; ++n)
      acc[m][n] = (f32x4){0.f, 0.f, 0.f, 0.f};

  for (int k0 = 0; k0 < K; k0 += 64) {
    if (k0) __syncthreads();
    #pragma unroll
    for (int s = 0; s < 4; ++s) {
      int rg = (s * 4 + wave) * 8;                 // 8-row group, covers 0..127
      __builtin_amdgcn_global_load_lds(
        (const AS1 void*)(aG + (size_t)rg * K + k0),
        (AS3 void*)&As[rg * 64], 16, 0, 0);
    }
    // B fragments: coalesced reg loads from L2 (fragment-ordered weights)
    bf16x8 bfr[2][4];
    const int kk0 = k0 >> 5;
    #pragma unroll
    for (int kk = 0; kk < 2; ++kk)
      #pragma unroll
      for (int n = 0; n < 4; ++n)
        bfr[kk][n] = *(const bf16x8*)(bW + ((size_t)n * kkt + kk0 + kk) * 512);
    __syncthreads();
    #pragma unroll
    for (int kk = 0; kk < 2; ++kk) {
      bf16x8 af[4];
      #pragma unroll
      for (int m = 0; m < 4; ++m)
        af[m] = *(const bf16x8*)&As[(wr + m * 16 + l15) * 64 + (((kk * 4 + lhi) ^ sw7)) * 8];
      #pragma unroll
      for (int m = 0; m < 4; ++m)
        #pragma unroll
        for (int n = 0; n < 4; ++n)
          acc[m][n] = __builtin_amdgcn_mfma_f32_16x16x32_bf16(af[m], bfr[kk][n], acc[m][n], 0, 0, 0);
    }
  }

  // epilogue: C(r,c) in acc[m][n][j]: r = brow+wr+m*16+lhi*4+j, c = bcol+wc+n*16+l15
  float bv[4];
  #pragma unroll
  for (int n = 0; n < 4; ++n) bv[n] = bias[bcol + wc + n * 16 + l15];
  #pragma unroll
  for (int m = 0; m < 4; ++m) {
    int rbase = brow + wr + m * 16 + lhi * 4;
    #pragma unroll
    for (int n = 0; n < 4; ++n) {
      int cc = bcol + wc + n * 16 + l15;
      #pragma unroll
      for (int j = 0; j < 4; ++j) {
        unsigned r = (unsigned)(rbase + j);
        float v = acc[m][n][j] + bv[n];
        if (EPI == 0) {
          int part = cc >> 9, head = (cc >> 5) & 15, d = cc & 31;
          ushort bvs = f2bf(v);
          if (part == 0)      qb[((size_t)head * NTOKP + r) * 32 + d] = bvs;
          else if (part == 1) kb[((size_t)head * NTOKP + r) * 32 + d] = bvs;
          else {
            unsigned w = r / 49u, nn = r - w * 49u;
            vb[(((size_t)(w * HEADS + head)) * 32 + d) * 64 + nn] = bvs;
          }
        } else if (EPI == 1) {
          // fast tanh-GELU: v * sigmoid(1.59577*v + 0.0713548*v^3)
          float u2 = v * (1.5957691216f + 0.0713548162f * v * v);
          float gl = __fdividef(v, 1.0f + __expf(-u2));
          ((ushort*)outp)[(size_t)r * N + cc] = f2bf(gl);
        } else if (EPI == 2) {
          unsigned w = r / 49u, nn = r - w * 49u;
          unsigned bb = w >> 6, wi = w & 63;
          unsigned wh = wi >> 3, ww = wi & 7;
          unsigned ii = nn / 7u, jj = nn - ii * 7u;
          unsigned dr = wh * 7 + ii + SS; if (dr >= Hh) dr -= Hh;  // roll(+3)
          unsigned dc = ww * 7 + jj + SS; if (dc >= Ww_) dc -= Ww_;
          size_t p = ((size_t)bb * Hh + dr) * Ww_ + dc;
          ((float*)outp)[p * Cc + cc] = resid[p * Cc + cc] + v;
        } else {
          float* o = (float*)outp;
          size_t idx = (size_t)r * Cc + cc;
          o[idx] = o[idx] + v;
        }
      }
    }
  }
}

// ---------- windowed attention: grid (NWIN, 4); 1 head per wave; NO barriers ----------
__global__ __launch_bounds__(256) void attn_kern(
    const ushort* __restrict__ qb, const ushort* __restrict__ kb,
    const ushort* __restrict__ vb, const float* __restrict__ be2,
    ushort* __restrict__ o_win)
{
  __shared__ ushort P[4][4096];                  // per-wave 64x64 bf16, XOR-swizzled
  const int wv = threadIdx.x >> 6, lane = threadIdx.x & 63;
  const int l15 = lane & 15, lhi = lane >> 4;
  const int w = blockIdx.x;
  const int head = blockIdx.y * 4 + wv;
  const int wi = w & 63, whh = wi >> 3, www = wi & 7;
  ushort* Pl = P[wv];

  int krg[4];
  #pragma unroll
  for (int n = 0; n < 4; ++n) {
    int key = n * 16 + l15;
    int rg = -1;
    if (key < Nn) {
      int ki = key / 7, kj = key - ki * 7;
      int rr = whh * 7 + ki, cc = www * 7 + kj;
      rg = (rr < 49 ? 0 : (rr < 53 ? 1 : 2)) * 3 + (cc < 49 ? 0 : (cc < 53 ? 1 : 2));
    }
    krg[n] = rg;
  }
  int qrg[4][4];
  #pragma unroll
  for (int m = 0; m < 4; ++m)
    #pragma unroll
    for (int j = 0; j < 4; ++j) {
      int q = m * 16 + lhi * 4 + j;
      int rg = -2;
      if (q < Nn) {
        int qi = q / 7, qj = q - qi * 7;
        int rr = whh * 7 + qi, cc = www * 7 + qj;
        rg = (rr < 49 ? 0 : (rr < 53 ? 1 : 2)) * 3 + (cc < 49 ? 0 : (cc < 53 ? 1 : 2));
      }
      qrg[m][j] = rg;
    }

  const ushort* qp = qb + ((size_t)head * NTOKP + (size_t)w * 49) * 32;
  const ushort* kp = kb + ((size_t)head * NTOKP + (size_t)w * 49) * 32;
  const ushort* vp = vb + (size_t)(w * HEADS + head) * 2048;   // [32][64] (V^T)
  const float*  bep = be2 + head * 4096;                       // [q][l15][n]

  bf16x8 qf[4], kf[4];
  #pragma unroll
  for (int m = 0; m < 4; ++m) {
    qf[m] = *(const bf16x8*)(qp + (m * 16 + l15) * 32 + lhi * 8);
    kf[m] = *(const bf16x8*)(kp + (m * 16 + l15) * 32 + lhi * 8);
  }
  f32x4 sa[4][4];
  #pragma unroll
  for (int m = 0; m < 4; ++m)
    #pragma unroll
    for (int n = 0; n < 4; ++n)
      sa[m][n] = __builtin_amdgcn_mfma_f32_16x16x32_bf16(qf[m], kf[n],
                   (f32x4){0.f, 0.f, 0.f, 0.f}, 0, 0, 0);

  #pragma unroll
  for (int m = 0; m < 4; ++m)
    #pragma unroll
    for (int j = 0; j < 4; ++j) {
      int q = m * 16 + lhi * 4 + j;
      int qr = qrg[m][j];
      f32x4 bev = *(const f32x4*)(bep + q * 64 + l15 * 4);
      float vv[4];
      float mx = -1e30f;
      #pragma unroll
      for (int n = 0; n < 4; ++n) {
        float v;
        if (qr >= 0 && krg[n] >= 0) {
          v = sa[m][n][j] * 0.17677669529663687f + bev[n];
          if (qr != krg[n]) v -= 100.0f;
        } else v = -1e30f;
        vv[n] = v;
        mx = fmaxf(mx, v);
      }
      #pragma unroll
      for (int off = 8; off; off >>= 1) mx = fmaxf(mx, __shfl_xor(mx, off));
      float sum = 0.f;
      #pragma unroll
      for (int n = 0; n < 4; ++n) { float p = __expf(vv[n] - mx); vv[n] = p; sum += p; }
      #pragma unroll
      for (int off = 8; off; off >>= 1) sum += __shfl_xor(sum, off);
      float is = 1.0f / sum;
      #pragma unroll
      for (int n = 0; n < 4; ++n) {
        int bo = (q * 128 + (n * 16 + l15) * 2) ^ ((q & 7) << 4);
        *(ushort*)((char*)Pl + bo) = f2bf(vv[n] * is);
      }
    }

  bf16x8 vf[2][2];
  #pragma unroll
  for (int nt = 0; nt < 2; ++nt)
    #pragma unroll
    for (int kt = 0; kt < 2; ++kt)
      vf[nt][kt] = *(const bf16x8*)(vp + (nt * 16 + l15) * 64 + kt * 32 + lhi * 8);
  f32x4 oa[4][2];
  #pragma unroll
  for (int m = 0; m < 4; ++m)
    #pragma unroll
    for (int nt = 0; nt < 2; ++nt)
      oa[m][nt] = (f32x4){0.f, 0.f, 0.f, 0.f};
  #pragma unroll
  for (int m = 0; m < 4; ++m) {
    int row = m * 16 + l15;
    #pragma unroll
    for (int kt = 0; kt < 2; ++kt) {
      int bo = (row * 128 + kt * 64 + lhi * 16) ^ ((row & 7) << 4);
      bf16x8 pa = *(const bf16x8*)((char*)Pl + bo);
      #pragma unroll
      for (int nt = 0; nt < 2; ++nt)
        oa[m][nt] = __builtin_amdgcn_mfma_f32_16x16x32_bf16(pa, vf[nt][kt], oa[m][nt], 0, 0, 0);
    }
  }
  #pragma unroll
  for (int m = 0; m < 4; ++m) {
    int q0 = m * 16 + lhi * 4;
    #pragma unroll
    for (int nt = 0; nt < 2; ++nt) {
      int d = nt * 16 + l15;
      #pragma unroll
      for (int j = 0; j < 4; ++j) {
        int q = q0 + j;
        if (q < Nn)
          o_win[((size_t)w * Nn + q) * Cc + head * HD + d] = f2bf(oa[m][nt][j]);
      }
    }
  }
}

// ---------- launch ----------
extern "C" void kernel_launch(void* const* d_in, const int* in_sizes, int n_in,
                              void* d_out, int out_size, void* d_ws, size_t ws_size,
                              hipStream_t stream) {
  const float* x      = (const float*)d_in[0];
  const float* n1g    = (const float*)d_in[1];
  const float* n1b    = (const float*)d_in[2];
  const float* qkv_w  = (const float*)d_in[3];
  const float* qkv_b  = (const float*)d_in[4];
  const float* relt   = (const float*)d_in[5];
  const float* proj_w = (const float*)d_in[6];
  const float* proj_b = (const float*)d_in[7];
  const float* n2g    = (const float*)d_in[8];
  const float* n2b    = (const float*)d_in[9];
  const float* fc1_w  = (const float*)d_in[10];
  const float* fc1_b  = (const float*)d_in[11];
  const float* fc2_w  = (const float*)d_in[12];
  const float* fc2_b  = (const float*)d_in[13];

  char* ws = (char*)d_ws;
  ushort* wq = (ushort*)ws; ws += (size_t)1536 * 512 * 2;
  ushort* wp = (ushort*)ws; ws += (size_t)512 * 512 * 2;
  ushort* w1 = (ushort*)ws; ws += (size_t)2048 * 512 * 2;
  ushort* w2 = (ushort*)ws; ws += (size_t)512 * 2048 * 2;
  float*  be = (float*)ws;  ws += (size_t)16 * 64 * 64 * 4;
  ushort* buf1 = (ushort*)ws; ws += (size_t)NTOK * 2048 * 2;         // yw / o_win / h1 (time-shared)
  ushort* qbuf = (ushort*)ws; ws += (size_t)16 * NTOKP * 32 * 2;     // Q head-major; also ln2 later
  ushort* kbuf = (ushort*)ws; ws += (size_t)16 * NTOKP * 32 * 2;     // K head-major
  ushort* vbuf = (ushort*)ws; ws += (size_t)NWIN * 16 * 32 * 64 * 2; // V^T windowed
  ushort* yw = buf1;
  ushort* o_win = buf1;
  ushort* h1 = buf1;
  ushort* l2buf = qbuf;   // NTOK*512 elems <= 16*NTOKP*32 elems
  float* xout = (float*)d_out;

  cvtwf_kern<<<2048, 256, 0, stream>>>(qkv_w, wq, proj_w, wp, fc1_w, w1, fc2_w, w2);
  prep_bias_kern<<<65536 / 256, 256, 0, stream>>>(relt, be);

  ln_kern<0><<<NTOK / 4, 256, 0, stream>>>(x, n1g, n1b, yw);
  // M = 100352 = 784*128; N/128: qkv 12, proj 4, fc1 16, fc2 4; all nwg % 8 == 0
  gemm_kern<0><<<dim3(12, 784), 256, 0, stream>>>(yw, wq, qkv_b, NTOK, 1536, 512,
                                                  nullptr, nullptr, qbuf, kbuf, vbuf);
  attn_kern<<<dim3(NWIN, 4), 256, 0, stream>>>(qbuf, kbuf, vbuf, be, o_win);
  gemm_kern<2><<<dim3(4, 784), 256, 0, stream>>>(o_win, wp, proj_b, NTOK, 512, 512,
                                                 xout, x, nullptr, nullptr, nullptr);
  ln_kern<1><<<NTOK / 4, 256, 0, stream>>>(xout, n2g, n2b, l2buf);
  gemm_kern<1><<<dim3(16, 784), 256, 0, stream>>>(l2buf, w1, fc1_b, NTOK, 2048, 512,
                                                  h1, nullptr, nullptr, nullptr, nullptr);
  gemm_kern<3><<<dim3(4, 784), 256, 0, stream>>>(h1, w2, fc2_b, NTOK, 512, 2048,
                                                 xout, xout, nullptr, nullptr, nullptr);
}

// Round 14
// 1298.884 us; speedup vs baseline: 1.0215x; 1.0215x over previous
//
#include <hip/hip_runtime.h>

// ---------- Swin block constants ----------
#define Bb   32
#define Hh   56
#define Ww_  56
#define Cc   512
#define HEADS 16
#define WS   7
#define SS   3
#define Nn   49          // window area
#define HD   32          // head dim
#define HID  2048
#define NWIN 2048        // B * nW
#define NTOK 100352      // B*H*W = NWIN*Nn
#define NTOKP 100416     // NTOK + 64 (pad rows so window-relative reads never go OOB)

typedef __attribute__((ext_vector_type(4))) float f32x4;
typedef __attribute__((ext_vector_type(8))) short bf16x8;

#define AS1 __attribute__((address_space(1)))
#define AS3 __attribute__((address_space(3)))

__device__ __forceinline__ ushort f2bf(float x) {
  union { float f; unsigned u; } un; un.f = x;
  unsigned u = un.u;
  return (ushort)((u + 0x7fffu + ((u >> 16) & 1u)) >> 16);
}

// ---------- weight convert to MFMA-fragment order ----------
// Bf[((n0*(K/32) + kk)*64 + lane)*8 + e] = bf16( W[(n0*16 + (lane&15))*K + kk*32 + (lane>>4)*8 + e] )
__device__ __forceinline__ void cvt_frag_seg(const float* __restrict__ s, ushort* __restrict__ d,
                                             int N, int K, int tid0, int stride) {
  int nch = (N * K) >> 3;
  int kc = K >> 3;            // 8-elem chunks per row
  int kkt = K >> 5;
  for (int c = tid0; c < nch; c += stride) {
    int row = c / kc, col8 = c - row * kc;
    int n0 = row >> 4, l15 = row & 15;
    int kk = col8 >> 2, lhi = col8 & 3;
    int lane = (lhi << 4) | l15;
    const float* sp = s + (size_t)c * 8;
    ushort* dp = d + (((size_t)(n0 * kkt + kk) * 64 + lane) * 8);
    #pragma unroll
    for (int e = 0; e < 8; ++e) dp[e] = f2bf(sp[e]);
  }
}

__global__ void cvtwf_kern(const float* __restrict__ s0, ushort* __restrict__ d0,
                           const float* __restrict__ s1, ushort* __restrict__ d1,
                           const float* __restrict__ s2, ushort* __restrict__ d2,
                           const float* __restrict__ s3, ushort* __restrict__ d3) {
  int tid0 = blockIdx.x * 256 + threadIdx.x;
  int stride = gridDim.x * 256;
  cvt_frag_seg(s0, d0, 1536, 512, tid0, stride);
  cvt_frag_seg(s1, d1, 512, 512, tid0, stride);
  cvt_frag_seg(s2, d2, 2048, 512, tid0, stride);
  cvt_frag_seg(s3, d3, 512, 2048, tid0, stride);
}

// bias in fragment order: be2[h][q][l15][n] (n -> key = n*16+l15); pads = 0 (masked later)
__global__ void prep_bias_kern(const float* __restrict__ table, float* __restrict__ be2) {
  int idx = blockIdx.x * 256 + threadIdx.x;  // 16*64*64 = 65536
  int h = idx >> 12, q = (idx >> 6) & 63, t = idx & 63;
  int l15 = t >> 2, n = t & 3;
  int key = n * 16 + l15;
  float v = 0.f;
  if (q < Nn && key < Nn) {
    int qi = q / 7, qj = q - qi * 7;
    int ki = key / 7, kj = key - ki * 7;
    v = table[((qi - ki + 6) * 13 + (qj - kj + 6)) * HEADS + h];
  }
  be2[idx] = v;
}

// ---------- LayerNorm (+ optional shift+window permute), fp32 in -> bf16 out ----------
template<int MODE>
__global__ __launch_bounds__(256) void ln_kern(const float* __restrict__ x,
    const float* __restrict__ g, const float* __restrict__ bsh,
    ushort* __restrict__ out)
{
  int row  = blockIdx.x * 4 + (threadIdx.x >> 6);
  int lane = threadIdx.x & 63;
  const float* src;
  if (MODE == 0) {
    unsigned w = (unsigned)row / 49u, n = (unsigned)row - w * 49u;
    unsigned bb = w >> 6, wi = w & 63;
    unsigned wh = wi >> 3, ww = wi & 7;
    unsigned i = n / 7u, j = n - i * 7u;
    unsigned sr = wh * 7 + i + SS; if (sr >= Hh) sr -= Hh;   // roll(-3)
    unsigned sc = ww * 7 + j + SS; if (sc >= Ww_) sc -= Ww_;
    src = x + ((size_t)(bb * Hh + sr) * Ww_ + sc) * Cc;
  } else {
    src = x + (size_t)row * Cc;
  }
  int c = lane * 8;
  f32x4 v0 = *(const f32x4*)(src + c);
  f32x4 v1 = *(const f32x4*)(src + c + 4);
  float s = 0.f, s2 = 0.f;
  #pragma unroll
  for (int e = 0; e < 4; ++e) { s += v0[e]; s2 += v0[e]*v0[e]; s += v1[e]; s2 += v1[e]*v1[e]; }
  #pragma unroll
  for (int off = 32; off; off >>= 1) { s += __shfl_xor(s, off); s2 += __shfl_xor(s2, off); }
  float mu = s * (1.f / 512.f);
  float rstd = rsqrtf(s2 * (1.f / 512.f) - mu * mu + 1e-5f);
  bf16x8 r;
  #pragma unroll
  for (int e = 0; e < 8; ++e) {
    float xv = (e < 4) ? v0[e] : v1[e - 4];
    r[e] = (short)f2bf((xv - mu) * rstd * g[c + e] + bsh[c + e]);
  }
  *(bf16x8*)(out + (size_t)row * Cc + c) = r;
}

// ---------- GEMM 128x128, 4 waves, BK=64: dbuf-A LDS (32 KB total), B streamed ----------
// R13 showed staging/LDS bytes are NOT the limiter — exposed per-iter load latency is.
// Now that B is streamed from L2 (fragment-ordered, coalesced reg loads), dbuf-A
// costs only 2x16KB = 32KB (same as R9's single buffer -> same residency) and moves
// the A-drain behind a full iteration of compute. ISSUE ORDER MATTERS: B loads are
// issued BEFORE the A(t+1) stage, so the compiler's wait for B is vmcnt(4) (A-prefetch
// stays in flight; vmcnt is FIFO). One plain __syncthreads per iter; no asm (m141).
// A-side both-sides chunk swizzle (rule #21) unchanged.
// EPI 0: QKV scatter (Q/K head-major, V^T windowed)  EPI 1: fast GELU->bf16
// EPI 2: proj+unshift+resid->f32  EPI 3: += f32
template<int EPI>
__global__ __launch_bounds__(256, 2) void gemm_kern(
    const ushort* __restrict__ A, const ushort* __restrict__ Bf,
    const float* __restrict__ bias, int M, int N, int K,
    void* __restrict__ outp, const float* __restrict__ resid,
    ushort* __restrict__ qb, ushort* __restrict__ kb, ushort* __restrict__ vb)
{
  __shared__ ushort As[2][128 * 64];
  const int tid = threadIdx.x;
  const int wave = tid >> 6, lane = tid & 63;
  const int l15 = lane & 15, lhi = lane >> 4;
  const int sw7 = l15 & 7;                    // fragment row & 7

  // T1: bijective XCD swizzle on flattened grid (nwg % 8 == 0 for all our grids)
  int gx = gridDim.x;
  int nwg = gx * gridDim.y;
  int orig = blockIdx.y * gx + blockIdx.x;
  int cpx = nwg >> 3;
  int wg = (orig & 7) * cpx + (orig >> 3);
  int bx = wg % gx, by = wg / gx;
  const int brow = by * 128, bcol = bx * 128;

  // wave -> 64x64 output sub-tile (2x2 wave grid)
  const int wr = (wave >> 1) * 64, wc = (wave & 1) * 64;

  const int srow = lane >> 3;                 // 0..7
  const int schk = ((lane & 7) ^ srow) * 8;   // pre-swizzled 16B-chunk offset (elems)
  const ushort* aG = A + (size_t)(brow + srow) * K + schk;

  const int kkt = K >> 5;
  const int nb0 = (bcol + wc) >> 4;           // wave's base 16-col group
  const ushort* bW = Bf + (size_t)nb0 * kkt * 512 + (size_t)lane * 8;

  auto stageA = [&](int kt, int sl) {
    #pragma unroll
    for (int s = 0; s < 4; ++s) {
      int rg = (s * 4 + wave) * 8;                 // 8-row group, covers 0..127
      __builtin_amdgcn_global_load_lds(
        (const AS1 void*)(aG + (size_t)rg * K + kt * 64),
        (AS3 void*)&As[sl][rg * 64], 16, 0, 0);
    }
  };

  f32x4 acc[4][4];
  #pragma unroll
  for (int m = 0; m < 4; ++m)
    #pragma unroll
    for (int n = 0; n < 4; ++n)
      acc[m][n] = (f32x4){0.f, 0.f, 0.f, 0.f};

  const int nt = K >> 6;

  // prologue: tile 0 -> slot 0, drained by barrier
  stageA(0, 0);
  __syncthreads();

  for (int t = 0; t < nt; ++t) {
    const int sl = t & 1;
    // B fragments FIRST (coalesced L2 reg-loads) so their wait leaves A-prefetch in flight
    bf16x8 bfr[2][4];
    #pragma unroll
    for (int kk = 0; kk < 2; ++kk)
      #pragma unroll
      for (int n = 0; n < 4; ++n)
        bfr[kk][n] = *(const bf16x8*)(bW + ((size_t)n * kkt + t * 2 + kk) * 512);
    if (t + 1 < nt) stageA(t + 1, sl ^ 1);         // prefetch next A tile, other slot
    const ushort* Ap = As[sl];
    #pragma unroll
    for (int kk = 0; kk < 2; ++kk) {
      bf16x8 af[4];
      #pragma unroll
      for (int m = 0; m < 4; ++m)
        af[m] = *(const bf16x8*)&Ap[(wr + m * 16 + l15) * 64 + (((kk * 4 + lhi) ^ sw7)) * 8];
      #pragma unroll
      for (int m = 0; m < 4; ++m)
        #pragma unroll
        for (int n = 0; n < 4; ++n)
          acc[m][n] = __builtin_amdgcn_mfma_f32_16x16x32_bf16(af[m], bfr[kk][n], acc[m][n], 0, 0, 0);
    }
    __syncthreads();   // drains A(t+1) — covered by B-wait + 8 ds_read + 32 MFMA; read fence
  }

  // epilogue: C(r,c) in acc[m][n][j]: r = brow+wr+m*16+lhi*4+j, c = bcol+wc+n*16+l15
  float bv[4];
  #pragma unroll
  for (int n = 0; n < 4; ++n) bv[n] = bias[bcol + wc + n * 16 + l15];
  #pragma unroll
  for (int m = 0; m < 4; ++m) {
    int rbase = brow + wr + m * 16 + lhi * 4;
    #pragma unroll
    for (int n = 0; n < 4; ++n) {
      int cc = bcol + wc + n * 16 + l15;
      #pragma unroll
      for (int j = 0; j < 4; ++j) {
        unsigned r = (unsigned)(rbase + j);
        float v = acc[m][n][j] + bv[n];
        if (EPI == 0) {
          int part = cc >> 9, head = (cc >> 5) & 15, d = cc & 31;
          ushort bvs = f2bf(v);
          if (part == 0)      qb[((size_t)head * NTOKP + r) * 32 + d] = bvs;
          else if (part == 1) kb[((size_t)head * NTOKP + r) * 32 + d] = bvs;
          else {
            unsigned w = r / 49u, nn = r - w * 49u;
            vb[(((size_t)(w * HEADS + head)) * 32 + d) * 64 + nn] = bvs;
          }
        } else if (EPI == 1) {
          // fast tanh-GELU: v * sigmoid(1.59577*v + 0.0713548*v^3)
          float u2 = v * (1.5957691216f + 0.0713548162f * v * v);
          float gl = __fdividef(v, 1.0f + __expf(-u2));
          ((ushort*)outp)[(size_t)r * N + cc] = f2bf(gl);
        } else if (EPI == 2) {
          unsigned w = r / 49u, nn = r - w * 49u;
          unsigned bb = w >> 6, wi = w & 63;
          unsigned wh = wi >> 3, ww = wi & 7;
          unsigned ii = nn / 7u, jj = nn - ii * 7u;
          unsigned dr = wh * 7 + ii + SS; if (dr >= Hh) dr -= Hh;  // roll(+3)
          unsigned dc = ww * 7 + jj + SS; if (dc >= Ww_) dc -= Ww_;
          size_t p = ((size_t)bb * Hh + dr) * Ww_ + dc;
          ((float*)outp)[p * Cc + cc] = resid[p * Cc + cc] + v;
        } else {
          float* o = (float*)outp;
          size_t idx = (size_t)r * Cc + cc;
          o[idx] = o[idx] + v;
        }
      }
    }
  }
}

// ---------- windowed attention: grid (NWIN, 4); 1 head per wave; NO barriers ----------
__global__ __launch_bounds__(256) void attn_kern(
    const ushort* __restrict__ qb, const ushort* __restrict__ kb,
    const ushort* __restrict__ vb, const float* __restrict__ be2,
    ushort* __restrict__ o_win)
{
  __shared__ ushort P[4][4096];                  // per-wave 64x64 bf16, XOR-swizzled
  const int wv = threadIdx.x >> 6, lane = threadIdx.x & 63;
  const int l15 = lane & 15, lhi = lane >> 4;
  const int w = blockIdx.x;
  const int head = blockIdx.y * 4 + wv;
  const int wi = w & 63, whh = wi >> 3, www = wi & 7;
  ushort* Pl = P[wv];

  int krg[4];
  #pragma unroll
  for (int n = 0; n < 4; ++n) {
    int key = n * 16 + l15;
    int rg = -1;
    if (key < Nn) {
      int ki = key / 7, kj = key - ki * 7;
      int rr = whh * 7 + ki, cc = www * 7 + kj;
      rg = (rr < 49 ? 0 : (rr < 53 ? 1 : 2)) * 3 + (cc < 49 ? 0 : (cc < 53 ? 1 : 2));
    }
    krg[n] = rg;
  }
  int qrg[4][4];
  #pragma unroll
  for (int m = 0; m < 4; ++m)
    #pragma unroll
    for (int j = 0; j < 4; ++j) {
      int q = m * 16 + lhi * 4 + j;
      int rg = -2;
      if (q < Nn) {
        int qi = q / 7, qj = q - qi * 7;
        int rr = whh * 7 + qi, cc = www * 7 + qj;
        rg = (rr < 49 ? 0 : (rr < 53 ? 1 : 2)) * 3 + (cc < 49 ? 0 : (cc < 53 ? 1 : 2));
      }
      qrg[m][j] = rg;
    }

  const ushort* qp = qb + ((size_t)head * NTOKP + (size_t)w * 49) * 32;
  const ushort* kp = kb + ((size_t)head * NTOKP + (size_t)w * 49) * 32;
  const ushort* vp = vb + (size_t)(w * HEADS + head) * 2048;   // [32][64] (V^T)
  const float*  bep = be2 + head * 4096;                       // [q][l15][n]

  bf16x8 qf[4], kf[4];
  #pragma unroll
  for (int m = 0; m < 4; ++m) {
    qf[m] = *(const bf16x8*)(qp + (m * 16 + l15) * 32 + lhi * 8);
    kf[m] = *(const bf16x8*)(kp + (m * 16 + l15) * 32 + lhi * 8);
  }
  f32x4 sa[4][4];
  #pragma unroll
  for (int m = 0; m < 4; ++m)
    #pragma unroll
    for (int n = 0; n < 4; ++n)
      sa[m][n] = __builtin_amdgcn_mfma_f32_16x16x32_bf16(qf[m], kf[n],
                   (f32x4){0.f, 0.f, 0.f, 0.f}, 0, 0, 0);

  #pragma unroll
  for (int m = 0; m < 4; ++m)
    #pragma unroll
    for (int j = 0; j < 4; ++j) {
      int q = m * 16 + lhi * 4 + j;
      int qr = qrg[m][j];
      f32x4 bev = *(const f32x4*)(bep + q * 64 + l15 * 4);
      float vv[4];
      float mx = -1e30f;
      #pragma unroll
      for (int n = 0; n < 4; ++n) {
        float v;
        if (qr >= 0 && krg[n] >= 0) {
          v = sa[m][n][j] * 0.17677669529663687f + bev[n];
          if (qr != krg[n]) v -= 100.0f;
        } else v = -1e30f;
        vv[n] = v;
        mx = fmaxf(mx, v);
      }
      #pragma unroll
      for (int off = 8; off; off >>= 1) mx = fmaxf(mx, __shfl_xor(mx, off));
      float sum = 0.f;
      #pragma unroll
      for (int n = 0; n < 4; ++n) { float p = __expf(vv[n] - mx); vv[n] = p; sum += p; }
      #pragma unroll
      for (int off = 8; off; off >>= 1) sum += __shfl_xor(sum, off);
      float is = 1.0f / sum;
      #pragma unroll
      for (int n = 0; n < 4; ++n) {
        int bo = (q * 128 + (n * 16 + l15) * 2) ^ ((q & 7) << 4);
        *(ushort*)((char*)Pl + bo) = f2bf(vv[n] * is);
      }
    }

  bf16x8 vf[2][2];
  #pragma unroll
  for (int nt = 0; nt < 2; ++nt)
    #pragma unroll
    for (int kt = 0; kt < 2; ++kt)
      vf[nt][kt] = *(const bf16x8*)(vp + (nt * 16 + l15) * 64 + kt * 32 + lhi * 8);
  f32x4 oa[4][2];
  #pragma unroll
  for (int m = 0; m < 4; ++m)
    #pragma unroll
    for (int nt = 0; nt < 2; ++nt)
      oa[m][nt] = (f32x4){0.f, 0.f, 0.f, 0.f};
  #pragma unroll
  for (int m = 0; m < 4; ++m) {
    int row = m * 16 + l15;
    #pragma unroll
    for (int kt = 0; kt < 2; ++kt) {
      int bo = (row * 128 + kt * 64 + lhi * 16) ^ ((row & 7) << 4);
      bf16x8 pa = *(const bf16x8*)((char*)Pl + bo);
      #pragma unroll
      for (int nt = 0; nt < 2; ++nt)
        oa[m][nt] = __builtin_amdgcn_mfma_f32_16x16x32_bf16(pa, vf[nt][kt], oa[m][nt], 0, 0, 0);
    }
  }
  #pragma unroll
  for (int m = 0; m < 4; ++m) {
    int q0 = m * 16 + lhi * 4;
    #pragma unroll
    for (int nt = 0; nt < 2; ++nt) {
      int d = nt * 16 + l15;
      #pragma unroll
      for (int j = 0; j < 4; ++j) {
        int q = q0 + j;
        if (q < Nn)
          o_win[((size_t)w * Nn + q) * Cc + head * HD + d] = f2bf(oa[m][nt][j]);
      }
    }
  }
}

// ---------- launch ----------
extern "C" void kernel_launch(void* const* d_in, const int* in_sizes, int n_in,
                              void* d_out, int out_size, void* d_ws, size_t ws_size,
                              hipStream_t stream) {
  const float* x      = (const float*)d_in[0];
  const float* n1g    = (const float*)d_in[1];
  const float* n1b    = (const float*)d_in[2];
  const float* qkv_w  = (const float*)d_in[3];
  const float* qkv_b  = (const float*)d_in[4];
  const float* relt   = (const float*)d_in[5];
  const float* proj_w = (const float*)d_in[6];
  const float* proj_b = (const float*)d_in[7];
  const float* n2g    = (const float*)d_in[8];
  const float* n2b    = (const float*)d_in[9];
  const float* fc1_w  = (const float*)d_in[10];
  const float* fc1_b  = (const float*)d_in[11];
  const float* fc2_w  = (const float*)d_in[12];
  const float* fc2_b  = (const float*)d_in[13];

  char* ws = (char*)d_ws;
  ushort* wq = (ushort*)ws; ws += (size_t)1536 * 512 * 2;
  ushort* wp = (ushort*)ws; ws += (size_t)512 * 512 * 2;
  ushort* w1 = (ushort*)ws; ws += (size_t)2048 * 512 * 2;
  ushort* w2 = (ushort*)ws; ws += (size_t)512 * 2048 * 2;
  float*  be = (float*)ws;  ws += (size_t)16 * 64 * 64 * 4;
  ushort* buf1 = (ushort*)ws; ws += (size_t)NTOK * 2048 * 2;         // yw / o_win / h1 (time-shared)
  ushort* qbuf = (ushort*)ws; ws += (size_t)16 * NTOKP * 32 * 2;     // Q head-major; also ln2 later
  ushort* kbuf = (ushort*)ws; ws += (size_t)16 * NTOKP * 32 * 2;     // K head-major
  ushort* vbuf = (ushort*)ws; ws += (size_t)NWIN * 16 * 32 * 64 * 2; // V^T windowed
  ushort* yw = buf1;
  ushort* o_win = buf1;
  ushort* h1 = buf1;
  ushort* l2buf = qbuf;   // NTOK*512 elems <= 16*NTOKP*32 elems
  float* xout = (float*)d_out;

  cvtwf_kern<<<2048, 256, 0, stream>>>(qkv_w, wq, proj_w, wp, fc1_w, w1, fc2_w, w2);
  prep_bias_kern<<<65536 / 256, 256, 0, stream>>>(relt, be);

  ln_kern<0><<<NTOK / 4, 256, 0, stream>>>(x, n1g, n1b, yw);
  // M = 100352 = 784*128; N/128: qkv 12, proj 4, fc1 16, fc2 4; all nwg % 8 == 0
  gemm_kern<0><<<dim3(12, 784), 256, 0, stream>>>(yw, wq, qkv_b, NTOK, 1536, 512,
                                                  nullptr, nullptr, qbuf, kbuf, vbuf);
  attn_kern<<<dim3(NWIN, 4), 256, 0, stream>>>(qbuf, kbuf, vbuf, be, o_win);
  gemm_kern<2><<<dim3(4, 784), 256, 0, stream>>>(o_win, wp, proj_b, NTOK, 512, 512,
                                                 xout, x, nullptr, nullptr, nullptr);
  ln_kern<1><<<NTOK / 4, 256, 0, stream>>>(xout, n2g, n2b, l2buf);
  gemm_kern<1><<<dim3(16, 784), 256, 0, stream>>>(l2buf, w1, fc1_b, NTOK, 2048, 512,
                                                  h1, nullptr, nullptr, nullptr, nullptr);
  gemm_kern<3><<<dim3(4, 784), 256, 0, stream>>>(h1, w2, fc2_b, NTOK, 512, 2048,
                                                 xout, xout, nullptr, nullptr, nullptr);
}